// Round 1
// baseline (917.157 us; speedup 1.0000x reference)
//
#include <hip/hip_runtime.h>

#define N_NODES 100000
#define N_EDGES 1600000
#define DIM     128
#define NGRAPH  64
#define NCLS    10

// ---------------- utility: zero a region of ws (int granularity) -------------
__global__ void k_zero(int* __restrict__ p, int n) {
  int i = blockIdx.x * blockDim.x + threadIdx.x;
  int stride = gridDim.x * blockDim.x;
  for (; i < n; i += stride) p[i] = 0;
}

// ---------------- degrees ----------------------------------------------------
__global__ void k_degrees(const int* __restrict__ src, const int* __restrict__ dst,
                          int* __restrict__ deg_out, int* __restrict__ deg_in) {
  int i = blockIdx.x * blockDim.x + threadIdx.x;
  int stride = gridDim.x * blockDim.x;
  for (; i < N_EDGES; i += stride) {
    atomicAdd(&deg_out[src[i]], 1);
    atomicAdd(&deg_in[dst[i]], 1);
  }
}

__global__ void k_invdeg(const int* __restrict__ deg_out, const int* __restrict__ deg_in,
                         float* __restrict__ inv_out, float* __restrict__ inv_in) {
  int i = blockIdx.x * blockDim.x + threadIdx.x;
  if (i < N_NODES) {
    int d = deg_out[i];
    int e = deg_in[i];
    inv_out[i] = d > 0 ? rsqrtf((float)d) : 0.f;
    inv_in[i]  = e > 0 ? rsqrtf((float)e) : 0.f;
  }
}

// ---------------- prefix scan of deg_in -> row_ptr ---------------------------
__global__ void k_blocksum(const int* __restrict__ deg_in, int* __restrict__ bsum) {
  __shared__ int s[256];
  int i = blockIdx.x * 256 + threadIdx.x;
  s[threadIdx.x] = (i < N_NODES) ? deg_in[i] : 0;
  __syncthreads();
  for (int off = 128; off > 0; off >>= 1) {
    if (threadIdx.x < off) s[threadIdx.x] += s[threadIdx.x + off];
    __syncthreads();
  }
  if (threadIdx.x == 0) bsum[blockIdx.x] = s[0];
}

__global__ void k_scan_bsum(int* __restrict__ bsum, int nb) {
  // single block, 512 threads, Hillis-Steele inclusive -> store exclusive
  __shared__ int s[512];
  int t = threadIdx.x;
  int v = (t < nb) ? bsum[t] : 0;
  s[t] = v;
  __syncthreads();
  for (int off = 1; off < 512; off <<= 1) {
    int x = (t >= off) ? s[t - off] : 0;
    __syncthreads();
    s[t] += x;
    __syncthreads();
  }
  if (t < nb) bsum[t] = s[t] - v;  // exclusive
}

__global__ void k_rowptr(const int* __restrict__ deg_in, const int* __restrict__ bsum,
                         int* __restrict__ row_ptr) {
  __shared__ int s[256];
  int t = threadIdx.x;
  int i = blockIdx.x * 256 + t;
  int v = (i < N_NODES) ? deg_in[i] : 0;
  s[t] = v;
  __syncthreads();
  for (int off = 1; off < 256; off <<= 1) {
    int x = (t >= off) ? s[t - off] : 0;
    __syncthreads();
    s[t] += x;
    __syncthreads();
  }
  if (i < N_NODES) row_ptr[i] = bsum[blockIdx.x] + s[t] - v;
  if (i == N_NODES - 1) row_ptr[N_NODES] = bsum[blockIdx.x] + s[t];
}

__global__ void k_fill(const int* __restrict__ src, const int* __restrict__ dst,
                       const int* __restrict__ row_ptr, int* __restrict__ fill,
                       int* __restrict__ csr_src) {
  int i = blockIdx.x * blockDim.x + threadIdx.x;
  int stride = gridDim.x * blockDim.x;
  for (; i < N_EDGES; i += stride) {
    int d = dst[i];
    int pos = row_ptr[d] + atomicAdd(&fill[d], 1);
    csr_src[pos] = src[i];
  }
}

// ---------------- prescale: hs = h * inv_out[row] ----------------------------
__global__ void k_prescale(const float* __restrict__ h, const float* __restrict__ inv_out,
                           float* __restrict__ out) {
  int idx = blockIdx.x * blockDim.x + threadIdx.x;  // float4 index
  if (idx < N_NODES * DIM / 4) {
    int row = idx >> 5;  // 32 float4 per row
    float4 v = ((const float4*)h)[idx];
    float s = inv_out[row];
    v.x *= s; v.y *= s; v.z *= s; v.w *= s;
    ((float4*)out)[idx] = v;
  }
}

// ---------------- gather-aggregate: agg[n] = inv_in[n] * sum_{e in-edges} hs[src] ----
__global__ void k_gather(const float* __restrict__ hs, const int* __restrict__ row_ptr,
                         const int* __restrict__ csr_src, const float* __restrict__ inv_in,
                         float* __restrict__ agg) {
  int wave = threadIdx.x >> 6;  // 4 waves / block, 1 node / wave
  int lane = threadIdx.x & 63;
  int n = blockIdx.x * 4 + wave;
  if (n >= N_NODES) return;
  int beg = row_ptr[n];
  int end = row_ptr[n + 1];
  float2 acc = make_float2(0.f, 0.f);
  for (int j = beg; j < end; ++j) {
    int s = csr_src[j];
    float2 v = ((const float2*)(hs + (size_t)s * DIM))[lane];
    acc.x += v.x;
    acc.y += v.y;
  }
  float sc = inv_in[n];
  acc.x *= sc;
  acc.y *= sc;
  ((float2*)(agg + (size_t)n * DIM))[lane] = acc;
}

// ---------------- GEMM: out = relu(A @ W + b) [* row_scale], fp32 ------------
// A: [N_NODES x 128], W: [128 x 128] row-major, tile: 64 rows x 128 cols / block
__global__ __launch_bounds__(256)
void k_gemm_bias_relu(const float* __restrict__ A, const float* __restrict__ W,
                      const float* __restrict__ bias, const float* __restrict__ row_scale,
                      float* __restrict__ out) {
  __shared__ float As[64][36];    // pad 36: 2-way bank alias only (free)
  __shared__ float Ws[32][132];   // pad 132: keeps float4 alignment, 2-way alias

  int tid = threadIdx.x;
  int tr = tid >> 4;   // 0..15 -> rows tr*4 .. tr*4+3
  int tc = tid & 15;   // 0..15 -> cols tc*4..+3 and 64+tc*4..+3
  int rowBase = blockIdx.x * 64;

  float acc[4][8] = {};

  for (int kk = 0; kk < DIM; kk += 32) {
    // stage A tile: 64 x 32 floats = 512 float4, 2 per thread
    #pragma unroll
    for (int l = 0; l < 2; ++l) {
      int li = tid + 256 * l;
      int r = li >> 3;
      int c4 = li & 7;
      int grow = rowBase + r;
      if (grow >= N_NODES) grow = N_NODES - 1;
      float4 v = *(const float4*)(A + (size_t)grow * DIM + kk + c4 * 4);
      *(float4*)&As[r][c4 * 4] = v;
    }
    // stage W tile: 32 x 128 floats = 1024 float4, 4 per thread
    #pragma unroll
    for (int l = 0; l < 4; ++l) {
      int li = tid + 256 * l;
      int r = li >> 5;
      int c4 = li & 31;
      float4 v = *(const float4*)(W + (size_t)(kk + r) * DIM + c4 * 4);
      *(float4*)&Ws[r][c4 * 4] = v;
    }
    __syncthreads();

    #pragma unroll
    for (int k = 0; k < 32; ++k) {
      float a[4];
      #pragma unroll
      for (int m = 0; m < 4; ++m) a[m] = As[tr * 4 + m][k];
      float4 w0 = *(const float4*)&Ws[k][tc * 4];
      float4 w1 = *(const float4*)&Ws[k][64 + tc * 4];
      float w[8] = {w0.x, w0.y, w0.z, w0.w, w1.x, w1.y, w1.z, w1.w};
      #pragma unroll
      for (int m = 0; m < 4; ++m)
        #pragma unroll
        for (int j = 0; j < 8; ++j) acc[m][j] = fmaf(a[m], w[j], acc[m][j]);
    }
    __syncthreads();
  }

  float4 b0 = *(const float4*)(bias + tc * 4);
  float4 b1 = *(const float4*)(bias + 64 + tc * 4);
  #pragma unroll
  for (int m = 0; m < 4; ++m) {
    int grow = rowBase + tr * 4 + m;
    if (grow >= N_NODES) continue;
    float s = row_scale ? row_scale[grow] : 1.f;
    float4 o0, o1;
    o0.x = fmaxf(acc[m][0] + b0.x, 0.f) * s;
    o0.y = fmaxf(acc[m][1] + b0.y, 0.f) * s;
    o0.z = fmaxf(acc[m][2] + b0.z, 0.f) * s;
    o0.w = fmaxf(acc[m][3] + b0.w, 0.f) * s;
    o1.x = fmaxf(acc[m][4] + b1.x, 0.f) * s;
    o1.y = fmaxf(acc[m][5] + b1.y, 0.f) * s;
    o1.z = fmaxf(acc[m][6] + b1.z, 0.f) * s;
    o1.w = fmaxf(acc[m][7] + b1.w, 0.f) * s;
    *(float4*)(out + (size_t)grow * DIM + tc * 4) = o0;
    *(float4*)(out + (size_t)grow * DIM + 64 + tc * 4) = o1;
  }
}

// ---------------- segmented mean-pool (graph_ids sorted) ---------------------
__global__ void k_pool(const float* __restrict__ h, const int* __restrict__ gid,
                       float* __restrict__ pool, float* __restrict__ cnt) {
  const int CH = 512;
  int start = blockIdx.x * CH;
  int end = start + CH;
  if (end > N_NODES) end = N_NODES;
  if (start >= N_NODES) return;
  int col = threadIdx.x;  // 128 threads
  float acc = 0.f;
  int g = gid[start];
  int seglen = 0;
  for (int i = start; i < end; ++i) {
    int gi = gid[i];
    if (gi != g) {
      atomicAdd(&pool[g * DIM + col], acc);
      if (col == 0) atomicAdd(&cnt[g], (float)seglen);
      acc = 0.f;
      seglen = 0;
      g = gi;
    }
    acc += h[(size_t)i * DIM + col];
    ++seglen;
  }
  atomicAdd(&pool[g * DIM + col], acc);
  if (col == 0) atomicAdd(&cnt[g], (float)seglen);
}

// ---------------- classifier: out = (pool/cnt) @ Wc + bc ---------------------
__global__ void k_classifier(const float* __restrict__ pool, const float* __restrict__ cnt,
                             const float* __restrict__ Wc, const float* __restrict__ bc,
                             float* __restrict__ out) {
  int t = threadIdx.x;
  if (t >= NGRAPH * NCLS) return;
  int g = t / NCLS, c = t % NCLS;
  float inv = 1.f / fmaxf(cnt[g], 1.f);
  float s = bc[c];
  for (int k = 0; k < DIM; ++k) s += pool[g * DIM + k] * inv * Wc[k * NCLS + c];
  out[g * NCLS + c] = s;
}

// -----------------------------------------------------------------------------
extern "C" void kernel_launch(void* const* d_in, const int* in_sizes, int n_in,
                              void* d_out, int out_size, void* d_ws, size_t ws_size,
                              hipStream_t stream) {
  const float* h   = (const float*)d_in[0];
  const int* src   = (const int*)d_in[1];
  const int* dst   = (const int*)d_in[2];
  const int* gid   = (const int*)d_in[3];
  const float* W1  = (const float*)d_in[4];
  const float* b1  = (const float*)d_in[5];
  const float* W2  = (const float*)d_in[6];
  const float* b2  = (const float*)d_in[7];
  const float* Wc  = (const float*)d_in[8];
  const float* bc  = (const float*)d_in[9];
  float* out = (float*)d_out;

  // ---- workspace layout (256B aligned slices) ----
  size_t off = 0;
  auto alloc = [&](size_t bytes) -> char* {
    char* p = (char*)d_ws + off;
    off += (bytes + 255) & ~(size_t)255;
    return p;
  };
  float* hbuf    = (float*)alloc((size_t)N_NODES * DIM * 4);
  float* aggbuf  = (float*)alloc((size_t)N_NODES * DIM * 4);
  int*   csr_src = (int*)alloc((size_t)N_EDGES * 4);
  int*   row_ptr = (int*)alloc((size_t)(N_NODES + 1) * 4);
  int*   bsum    = (int*)alloc(512 * 4);
  // zeroed region begins here:
  char* zero_start = (char*)d_ws + off;
  int*   deg_out = (int*)alloc((size_t)N_NODES * 4);
  int*   deg_in  = (int*)alloc((size_t)N_NODES * 4);
  int*   fill    = (int*)alloc((size_t)N_NODES * 4);
  float* pool    = (float*)alloc((size_t)NGRAPH * DIM * 4);
  float* cnt     = (float*)alloc((size_t)NGRAPH * 4);
  char* zero_end = (char*)d_ws + off;
  // zeroed region ends here
  float* inv_out = (float*)alloc((size_t)N_NODES * 4);
  float* inv_in  = (float*)alloc((size_t)N_NODES * 4);
  (void)ws_size; (void)in_sizes; (void)n_in; (void)out_size;

  int zero_ints = (int)((zero_end - zero_start) / 4);
  const int NB = (N_NODES + 255) / 256;  // 391

  // 1. zero the accumulated buffers (ws is poisoned 0xAA before every launch)
  k_zero<<<512, 256, 0, stream>>>((int*)zero_start, zero_ints);
  // 2. degree histograms
  k_degrees<<<2048, 256, 0, stream>>>(src, dst, deg_out, deg_in);
  // 3. normalization factors
  k_invdeg<<<NB, 256, 0, stream>>>(deg_out, deg_in, inv_out, inv_in);
  // 4-6. exclusive scan of deg_in -> row_ptr
  k_blocksum<<<NB, 256, 0, stream>>>(deg_in, bsum);
  k_scan_bsum<<<1, 512, 0, stream>>>(bsum, NB);
  k_rowptr<<<NB, 256, 0, stream>>>(deg_in, bsum, row_ptr);
  // 7. CSR fill (src ids bucketed by dst)
  k_fill<<<2048, 256, 0, stream>>>(src, dst, row_ptr, fill, csr_src);
  // 8. hs = h * inv_out  (src-side norm, layer 1)
  k_prescale<<<(N_NODES * DIM / 4 + 255) / 256, 256, 0, stream>>>(h, inv_out, hbuf);
  // 9. layer-1 aggregate
  k_gather<<<(N_NODES + 3) / 4, 256, 0, stream>>>(hbuf, row_ptr, csr_src, inv_in, aggbuf);
  // 10. layer-1 GEMM + bias + relu, fused with next layer's src-side norm
  k_gemm_bias_relu<<<(N_NODES + 63) / 64, 256, 0, stream>>>(aggbuf, W1, b1, inv_out, hbuf);
  // 11. layer-2 aggregate
  k_gather<<<(N_NODES + 3) / 4, 256, 0, stream>>>(hbuf, row_ptr, csr_src, inv_in, aggbuf);
  // 12. layer-2 GEMM + bias + relu (no scale; feeds pooling)
  k_gemm_bias_relu<<<(N_NODES + 63) / 64, 256, 0, stream>>>(aggbuf, W2, b2, nullptr, hbuf);
  // 13. mean-pool by graph id (sorted -> segmented partial sums, few atomics)
  k_pool<<<(N_NODES + 511) / 512, 128, 0, stream>>>(hbuf, gid, pool, cnt);
  // 14. classifier
  k_classifier<<<1, 640, 0, stream>>>(pool, cnt, Wc, bc, out);
}

// Round 2
// 876.757 us; speedup vs baseline: 1.0461x; 1.0461x over previous
//
#include <hip/hip_runtime.h>

#define N_NODES 100000
#define N_EDGES 1600000
#define DIM     128
#define NGRAPH  64
#define NCLS    10

typedef __bf16 bf16x8 __attribute__((ext_vector_type(8)));
typedef float  f32x4  __attribute__((ext_vector_type(4)));

// ---- bf16 pack/unpack helpers (manual RNE, no __bf16 arithmetic) ------------
__device__ __forceinline__ ushort f2bf(float x) {
  uint b = __float_as_uint(x);
  b += 0x7fffu + ((b >> 16) & 1u);
  return (ushort)(b >> 16);
}
__device__ __forceinline__ uint pack2(float lo, float hi) {
  return (uint)f2bf(lo) | ((uint)f2bf(hi) << 16);
}
__device__ __forceinline__ float unlo(uint u) { return __uint_as_float(u << 16); }
__device__ __forceinline__ float unhi(uint u) { return __uint_as_float(u & 0xffff0000u); }

// ---------------- utility: zero a region of ws (int granularity) -------------
__global__ void k_zero(int* __restrict__ p, int n) {
  int i = blockIdx.x * blockDim.x + threadIdx.x;
  int stride = gridDim.x * blockDim.x;
  for (; i < n; i += stride) p[i] = 0;
}

// ---------------- degrees ----------------------------------------------------
__global__ void k_degrees(const int* __restrict__ src, const int* __restrict__ dst,
                          int* __restrict__ deg_out, int* __restrict__ deg_in) {
  int i = blockIdx.x * blockDim.x + threadIdx.x;
  int stride = gridDim.x * blockDim.x;
  for (; i < N_EDGES; i += stride) {
    atomicAdd(&deg_out[src[i]], 1);
    atomicAdd(&deg_in[dst[i]], 1);
  }
}

// ---------------- prefix scan of deg_in -> row_ptr ---------------------------
__global__ void k_blocksum(const int* __restrict__ deg_in, int* __restrict__ bsum) {
  __shared__ int s[256];
  int i = blockIdx.x * 256 + threadIdx.x;
  s[threadIdx.x] = (i < N_NODES) ? deg_in[i] : 0;
  __syncthreads();
  for (int off = 128; off > 0; off >>= 1) {
    if (threadIdx.x < off) s[threadIdx.x] += s[threadIdx.x + off];
    __syncthreads();
  }
  if (threadIdx.x == 0) bsum[blockIdx.x] = s[0];
}

__global__ void k_scan_bsum(int* __restrict__ bsum, int nb) {
  __shared__ int s[512];
  int t = threadIdx.x;
  int v = (t < nb) ? bsum[t] : 0;
  s[t] = v;
  __syncthreads();
  for (int off = 1; off < 512; off <<= 1) {
    int x = (t >= off) ? s[t - off] : 0;
    __syncthreads();
    s[t] += x;
    __syncthreads();
  }
  if (t < nb) bsum[t] = s[t] - v;  // exclusive
}

__global__ void k_rowptr(const int* __restrict__ deg_in, const int* __restrict__ bsum,
                         int* __restrict__ row_ptr) {
  __shared__ int s[256];
  int t = threadIdx.x;
  int i = blockIdx.x * 256 + t;
  int v = (i < N_NODES) ? deg_in[i] : 0;
  s[t] = v;
  __syncthreads();
  for (int off = 1; off < 256; off <<= 1) {
    int x = (t >= off) ? s[t - off] : 0;
    __syncthreads();
    s[t] += x;
    __syncthreads();
  }
  if (i < N_NODES) row_ptr[i] = bsum[blockIdx.x] + s[t] - v;
  if (i == N_NODES - 1) row_ptr[N_NODES] = bsum[blockIdx.x] + s[t];
}

__global__ void k_fill(const int* __restrict__ src, const int* __restrict__ dst,
                       const int* __restrict__ row_ptr, int* __restrict__ fill,
                       int* __restrict__ csr_src) {
  int i = blockIdx.x * blockDim.x + threadIdx.x;
  int stride = gridDim.x * blockDim.x;
  for (; i < N_EDGES; i += stride) {
    int d = dst[i];
    int pos = row_ptr[d] + atomicAdd(&fill[d], 1);
    csr_src[pos] = src[i];
  }
}

// ---------------- W -> bf16 transposed (B^T layout: Wt[c][k]) ----------------
__global__ void k_convW(const float* __restrict__ W1, const float* __restrict__ W2,
                        ushort* __restrict__ Wt1, ushort* __restrict__ Wt2) {
  int idx = blockIdx.x * 256 + threadIdx.x;  // 0 .. 2*16384
  const float* W = (idx < 16384) ? W1 : W2;
  ushort* Wt = (idx < 16384) ? Wt1 : Wt2;
  int t = idx & 16383;
  int c = t >> 7, k = t & 127;
  Wt[c * 128 + k] = f2bf(W[k * 128 + c]);
}

// ---------------- prescale: hs = bf16(h * inv_out[row]) ----------------------
__global__ void k_prescale(const float* __restrict__ h, const int* __restrict__ deg_out,
                           uint* __restrict__ out) {
  int idx = blockIdx.x * blockDim.x + threadIdx.x;  // packed-pair index
  if (idx < N_NODES * 64) {
    int row = idx >> 6;
    int d = deg_out[row];
    float s = d > 0 ? rsqrtf((float)d) : 0.f;
    float2 v = ((const float2*)h)[idx];
    out[idx] = pack2(v.x * s, v.y * s);
  }
}

// ---------------- gather-aggregate (bf16 rows, fp32 accum) -------------------
// agg[n] = bf16( inv_in[n] * sum_{e in-edges(n)} hs[src_e] )
__global__ void k_gather(const uint* __restrict__ hs, const int* __restrict__ row_ptr,
                         const int* __restrict__ csr_src, const int* __restrict__ deg_in,
                         uint* __restrict__ agg) {
  int wave = threadIdx.x >> 6;  // 4 waves / block, 1 node / wave
  int lane = threadIdx.x & 63;
  int n = blockIdx.x * 4 + wave;
  if (n >= N_NODES) return;
  int beg = row_ptr[n];
  int end = row_ptr[n + 1];
  float ax = 0.f, ay = 0.f;
  for (int j = beg; j < end; ++j) {
    int s = csr_src[j];
    uint u = hs[(size_t)s * 64 + lane];
    ax += unlo(u);
    ay += unhi(u);
  }
  int d = end - beg;
  float sc = d > 0 ? rsqrtf((float)d) : 0.f;
  (void)deg_in;
  agg[(size_t)n * 64 + lane] = pack2(ax * sc, ay * sc);
}

// ---------------- MFMA GEMM: out = bf16(relu(A@W + b) [* invsqrt(deg)]) ------
// A: [N x 128] bf16 row-major. Wt: [128 x 128] bf16, Wt[c][k] = W[k][c] (B^T).
// One wave per 16-row strip; all 128 output cols; B frags held in registers.
__global__ __launch_bounds__(256)
void k_gemm(const ushort* __restrict__ A, const ushort* __restrict__ Wt,
            const float* __restrict__ bias, const int* __restrict__ deg_scale,
            ushort* __restrict__ out) {
  int wave = threadIdx.x >> 6, lane = threadIdx.x & 63;
  int strip = blockIdx.x * 4 + wave;
  if (strip >= N_NODES / 16) return;  // 6250 exact strips
  int row0 = strip * 16;
  int lr = lane & 15;   // A-row / B-col selector within 16
  int lk = lane >> 4;   // k-octet selector

  bf16x8 bfrag[4][8];
  #pragma unroll
  for (int ks = 0; ks < 4; ++ks)
    #pragma unroll
    for (int c = 0; c < 8; ++c)
      bfrag[ks][c] = *(const bf16x8*)(Wt + (size_t)(c * 16 + lr) * 128 + ks * 32 + lk * 8);

  f32x4 acc[8] = {};
  #pragma unroll
  for (int ks = 0; ks < 4; ++ks) {
    bf16x8 afrag = *(const bf16x8*)(A + (size_t)(row0 + lr) * 128 + ks * 32 + lk * 8);
    #pragma unroll
    for (int c = 0; c < 8; ++c)
      acc[c] = __builtin_amdgcn_mfma_f32_16x16x32_bf16(afrag, bfrag[ks][c], acc[c], 0, 0, 0);
  }

  // C/D layout: col = lane&15 (tile-local), row = (lane>>4)*4 + reg
  #pragma unroll
  for (int r = 0; r < 4; ++r) {
    int row = row0 + lk * 4 + r;
    float s = 1.f;
    if (deg_scale) {
      int d = deg_scale[row];
      s = d > 0 ? rsqrtf((float)d) : 0.f;
    }
    #pragma unroll
    for (int c = 0; c < 8; ++c) {
      int col = c * 16 + lr;
      float v = fmaxf(acc[c][r] + bias[col], 0.f) * s;
      out[(size_t)row * 128 + col] = f2bf(v);
    }
  }
}

// ---------------- segmented mean-pool (graph_ids sorted, bf16 input) ---------
__global__ void k_pool(const ushort* __restrict__ h, const int* __restrict__ gid,
                       float* __restrict__ pool, float* __restrict__ cnt) {
  const int CH = 512;
  int start = blockIdx.x * CH;
  int end = start + CH;
  if (end > N_NODES) end = N_NODES;
  if (start >= N_NODES) return;
  int c2 = threadIdx.x;  // 0..63: packed column pair
  float ax = 0.f, ay = 0.f;
  int g = gid[start];
  int seglen = 0;
  const uint* hu = (const uint*)h;
  for (int i = start; i < end; ++i) {
    int gi = gid[i];
    if (gi != g) {
      atomicAdd(&pool[g * DIM + 2 * c2], ax);
      atomicAdd(&pool[g * DIM + 2 * c2 + 1], ay);
      if (c2 == 0) atomicAdd(&cnt[g], (float)seglen);
      ax = ay = 0.f;
      seglen = 0;
      g = gi;
    }
    uint u = hu[(size_t)i * 64 + c2];
    ax += unlo(u);
    ay += unhi(u);
    ++seglen;
  }
  atomicAdd(&pool[g * DIM + 2 * c2], ax);
  atomicAdd(&pool[g * DIM + 2 * c2 + 1], ay);
  if (c2 == 0) atomicAdd(&cnt[g], (float)seglen);
}

// ---------------- classifier: out = (pool/cnt) @ Wc + bc ---------------------
__global__ void k_classifier(const float* __restrict__ pool, const float* __restrict__ cnt,
                             const float* __restrict__ Wc, const float* __restrict__ bc,
                             float* __restrict__ out) {
  int t = threadIdx.x;
  if (t >= NGRAPH * NCLS) return;
  int g = t / NCLS, c = t % NCLS;
  float inv = 1.f / fmaxf(cnt[g], 1.f);
  float s = bc[c];
  for (int k = 0; k < DIM; ++k) s += pool[g * DIM + k] * inv * Wc[k * NCLS + c];
  out[g * NCLS + c] = s;
}

// -----------------------------------------------------------------------------
extern "C" void kernel_launch(void* const* d_in, const int* in_sizes, int n_in,
                              void* d_out, int out_size, void* d_ws, size_t ws_size,
                              hipStream_t stream) {
  const float* h   = (const float*)d_in[0];
  const int* src   = (const int*)d_in[1];
  const int* dst   = (const int*)d_in[2];
  const int* gid   = (const int*)d_in[3];
  const float* W1  = (const float*)d_in[4];
  const float* b1  = (const float*)d_in[5];
  const float* W2  = (const float*)d_in[6];
  const float* b2  = (const float*)d_in[7];
  const float* Wc  = (const float*)d_in[8];
  const float* bc  = (const float*)d_in[9];
  float* out = (float*)d_out;

  size_t off = 0;
  auto alloc = [&](size_t bytes) -> char* {
    char* p = (char*)d_ws + off;
    off += (bytes + 255) & ~(size_t)255;
    return p;
  };
  ushort* hbuf    = (ushort*)alloc((size_t)N_NODES * DIM * 2);  // bf16 features
  ushort* aggbuf  = (ushort*)alloc((size_t)N_NODES * DIM * 2);  // bf16 aggregate
  ushort* h2buf   = (ushort*)alloc((size_t)N_NODES * DIM * 2);  // bf16 layer-2 out
  int*    csr_src = (int*)alloc((size_t)N_EDGES * 4);
  int*    row_ptr = (int*)alloc((size_t)(N_NODES + 1) * 4);
  int*    bsum    = (int*)alloc(512 * 4);
  ushort* Wt1     = (ushort*)alloc(16384 * 2);
  ushort* Wt2     = (ushort*)alloc(16384 * 2);
  // zeroed region:
  char* zero_start = (char*)d_ws + off;
  int*   deg_out = (int*)alloc((size_t)N_NODES * 4);
  int*   deg_in  = (int*)alloc((size_t)N_NODES * 4);
  int*   fill    = (int*)alloc((size_t)N_NODES * 4);
  float* pool    = (float*)alloc((size_t)NGRAPH * DIM * 4);
  float* cnt     = (float*)alloc((size_t)NGRAPH * 4);
  char* zero_end = (char*)d_ws + off;
  (void)ws_size; (void)in_sizes; (void)n_in; (void)out_size;

  int zero_ints = (int)((zero_end - zero_start) / 4);
  const int NB = (N_NODES + 255) / 256;  // 391

  k_zero<<<512, 256, 0, stream>>>((int*)zero_start, zero_ints);
  k_degrees<<<2048, 256, 0, stream>>>(src, dst, deg_out, deg_in);
  k_blocksum<<<NB, 256, 0, stream>>>(deg_in, bsum);
  k_scan_bsum<<<1, 512, 0, stream>>>(bsum, NB);
  k_rowptr<<<NB, 256, 0, stream>>>(deg_in, bsum, row_ptr);
  k_fill<<<2048, 256, 0, stream>>>(src, dst, row_ptr, fill, csr_src);
  k_convW<<<128, 256, 0, stream>>>(W1, W2, Wt1, Wt2);
  // layer 1
  k_prescale<<<(N_NODES * 64 + 255) / 256, 256, 0, stream>>>(h, deg_out, (uint*)hbuf);
  k_gather<<<(N_NODES + 3) / 4, 256, 0, stream>>>((const uint*)hbuf, row_ptr, csr_src,
                                                  deg_in, (uint*)aggbuf);
  k_gemm<<<(N_NODES / 16 + 3) / 4, 256, 0, stream>>>(aggbuf, Wt1, b1, deg_out, hbuf);
  // layer 2 (hbuf already carries next layer's src-side norm from the epilogue)
  k_gather<<<(N_NODES + 3) / 4, 256, 0, stream>>>((const uint*)hbuf, row_ptr, csr_src,
                                                  deg_in, (uint*)aggbuf);
  k_gemm<<<(N_NODES / 16 + 3) / 4, 256, 0, stream>>>(aggbuf, Wt2, b2, nullptr, h2buf);
  // pool + classify
  k_pool<<<(N_NODES + 511) / 512, 64, 0, stream>>>(h2buf, gid, pool, cnt);
  k_classifier<<<1, 640, 0, stream>>>(pool, cnt, Wc, bc, out);
}

// Round 3
// 582.415 us; speedup vs baseline: 1.5747x; 1.5054x over previous
//
#include <hip/hip_runtime.h>

#define N_NODES 100000
#define N_EDGES 1600000
#define DIM     128
#define NGRAPH  64
#define NCLS    10
#define ZROW    N_NODES   // zeroed pad row id in hbuf

typedef __bf16 bf16x8 __attribute__((ext_vector_type(8)));
typedef float  f32x4  __attribute__((ext_vector_type(4)));

// ---- bf16 pack/unpack helpers (manual RNE) ----------------------------------
__device__ __forceinline__ ushort f2bf(float x) {
  uint b = __float_as_uint(x);
  b += 0x7fffu + ((b >> 16) & 1u);
  return (ushort)(b >> 16);
}
__device__ __forceinline__ uint pack2(float lo, float hi) {
  return (uint)f2bf(lo) | ((uint)f2bf(hi) << 16);
}
__device__ __forceinline__ float unlo(uint u) { return __uint_as_float(u << 16); }
__device__ __forceinline__ float unhi(uint u) { return __uint_as_float(u & 0xffff0000u); }

__device__ __forceinline__ void acc8(float* a, uint4 u) {
  a[0] += unlo(u.x); a[1] += unhi(u.x);
  a[2] += unlo(u.y); a[3] += unhi(u.y);
  a[4] += unlo(u.z); a[5] += unhi(u.z);
  a[6] += unlo(u.w); a[7] += unhi(u.w);
}

// ---------------- utility: zero a region of ws -------------------------------
__global__ void k_zero(int* __restrict__ p, int n) {
  int i = blockIdx.x * blockDim.x + threadIdx.x;
  int stride = gridDim.x * blockDim.x;
  for (; i < n; i += stride) p[i] = 0;
}

// ---------------- degrees (int4: 4 edges / thread) ---------------------------
__global__ void k_degrees(const int4* __restrict__ src4, const int4* __restrict__ dst4,
                          int* __restrict__ deg_out, int* __restrict__ deg_in) {
  int i = blockIdx.x * blockDim.x + threadIdx.x;
  if (i < N_EDGES / 4) {
    int4 s = src4[i];
    int4 d = dst4[i];
    atomicAdd(&deg_out[s.x], 1); atomicAdd(&deg_out[s.y], 1);
    atomicAdd(&deg_out[s.z], 1); atomicAdd(&deg_out[s.w], 1);
    atomicAdd(&deg_in[d.x], 1);  atomicAdd(&deg_in[d.y], 1);
    atomicAdd(&deg_in[d.z], 1);  atomicAdd(&deg_in[d.w], 1);
  }
}

// ---------------- prefix scan of deg_in -> row_ptr ---------------------------
__global__ void k_blocksum(const int* __restrict__ deg_in, int* __restrict__ bsum) {
  __shared__ int s[256];
  int i = blockIdx.x * 256 + threadIdx.x;
  s[threadIdx.x] = (i < N_NODES) ? deg_in[i] : 0;
  __syncthreads();
  for (int off = 128; off > 0; off >>= 1) {
    if (threadIdx.x < off) s[threadIdx.x] += s[threadIdx.x + off];
    __syncthreads();
  }
  if (threadIdx.x == 0) bsum[blockIdx.x] = s[0];
}

__global__ void k_scan_bsum(int* __restrict__ bsum, int nb) {
  __shared__ int s[512];
  int t = threadIdx.x;
  int v = (t < nb) ? bsum[t] : 0;
  s[t] = v;
  __syncthreads();
  for (int off = 1; off < 512; off <<= 1) {
    int x = (t >= off) ? s[t - off] : 0;
    __syncthreads();
    s[t] += x;
    __syncthreads();
  }
  if (t < nb) bsum[t] = s[t] - v;  // exclusive
}

__global__ void k_rowptr(const int* __restrict__ deg_in, const int* __restrict__ bsum,
                         int* __restrict__ row_ptr) {
  __shared__ int s[256];
  int t = threadIdx.x;
  int i = blockIdx.x * 256 + t;
  int v = (i < N_NODES) ? deg_in[i] : 0;
  s[t] = v;
  __syncthreads();
  for (int off = 1; off < 256; off <<= 1) {
    int x = (t >= off) ? s[t - off] : 0;
    __syncthreads();
    s[t] += x;
    __syncthreads();
  }
  if (i < N_NODES) row_ptr[i] = bsum[blockIdx.x] + s[t] - v;
  if (i == N_NODES - 1) row_ptr[N_NODES] = bsum[blockIdx.x] + s[t];
}

__global__ void k_fill(const int4* __restrict__ src4, const int4* __restrict__ dst4,
                       const int* __restrict__ row_ptr, int* __restrict__ fill,
                       int* __restrict__ csr_src) {
  int i = blockIdx.x * blockDim.x + threadIdx.x;
  if (i < N_EDGES / 4) {
    int4 s = src4[i];
    int4 d = dst4[i];
    int p0 = row_ptr[d.x] + atomicAdd(&fill[d.x], 1);
    int p1 = row_ptr[d.y] + atomicAdd(&fill[d.y], 1);
    int p2 = row_ptr[d.z] + atomicAdd(&fill[d.z], 1);
    int p3 = row_ptr[d.w] + atomicAdd(&fill[d.w], 1);
    csr_src[p0] = s.x; csr_src[p1] = s.y; csr_src[p2] = s.z; csr_src[p3] = s.w;
  }
}

// ---------------- W -> bf16 transposed (B^T layout: Wt[c][k]) ----------------
__global__ void k_convW(const float* __restrict__ W1, const float* __restrict__ W2,
                        ushort* __restrict__ Wt1, ushort* __restrict__ Wt2) {
  int idx = blockIdx.x * 256 + threadIdx.x;  // 0 .. 2*16384
  const float* W = (idx < 16384) ? W1 : W2;
  ushort* Wt = (idx < 16384) ? Wt1 : Wt2;
  int t = idx & 16383;
  int c = t >> 7, k = t & 127;
  Wt[c * 128 + k] = f2bf(W[k * 128 + c]);
}

// ---------------- prescale: hs = bf16(h * rsqrt(deg_out[row])) ---------------
__global__ void k_prescale(const float4* __restrict__ h4, const int* __restrict__ deg_out,
                           uint4* __restrict__ out4) {
  int idx = blockIdx.x * blockDim.x + threadIdx.x;  // uint4 index
  if (idx < N_NODES * 16) {
    int row = idx >> 4;
    int d = deg_out[row];
    float s = d > 0 ? rsqrtf((float)d) : 0.f;
    float4 v0 = h4[idx * 2];
    float4 v1 = h4[idx * 2 + 1];
    uint4 o;
    o.x = pack2(v0.x * s, v0.y * s);
    o.y = pack2(v0.z * s, v0.w * s);
    o.z = pack2(v1.x * s, v1.y * s);
    o.w = pack2(v1.z * s, v1.w * s);
    out4[idx] = o;
  }
}

// ---------------- gather-aggregate, MLP-optimized ----------------------------
// One node per wave. Wave = 4 edge-slots (sub) x 16 column-slots (li, uint4).
// Indices preloaded 64 at a time (one coalesced load), broadcast via shfl.
// 16 edges / iteration, 4 independent 16B loads per lane in flight.
__global__ __launch_bounds__(256)
void k_gather(const uint* __restrict__ hs, const int* __restrict__ row_ptr,
              const int* __restrict__ csr_src, uint* __restrict__ agg) {
  int wave = threadIdx.x >> 6;
  int lane = threadIdx.x & 63;
  int n = blockIdx.x * 4 + wave;
  if (n >= N_NODES) return;
  int beg = row_ptr[n];
  int end = row_ptr[n + 1];
  int deg = end - beg;
  int sub = lane >> 4;   // edge slot 0..3
  int li  = lane & 15;   // uint4 column slot

  float a[8] = {};

  for (int cb = 0; cb < deg; cb += 64) {
    int cdeg = min(64, deg - cb);
    int myidx = (lane < cdeg) ? csr_src[beg + cb + lane] : ZROW;
    for (int e = 0; e < cdeg; e += 16) {
      int s0 = __shfl(myidx, e + sub);
      int s1 = __shfl(myidx, e + 4 + sub);
      int s2 = __shfl(myidx, e + 8 + sub);
      int s3 = __shfl(myidx, e + 12 + sub);
      uint4 u0 = *(const uint4*)(hs + (size_t)s0 * 64 + li * 4);
      uint4 u1 = *(const uint4*)(hs + (size_t)s1 * 64 + li * 4);
      uint4 u2 = *(const uint4*)(hs + (size_t)s2 * 64 + li * 4);
      uint4 u3 = *(const uint4*)(hs + (size_t)s3 * 64 + li * 4);
      acc8(a, u0); acc8(a, u1); acc8(a, u2); acc8(a, u3);
    }
  }

  // reduce across the 4 edge slots (lanes li, li+16, li+32, li+48)
  #pragma unroll
  for (int k = 0; k < 8; ++k) {
    a[k] += __shfl_xor(a[k], 16);
    a[k] += __shfl_xor(a[k], 32);
  }

  if (sub == 0) {
    float sc = deg > 0 ? rsqrtf((float)deg) : 0.f;
    uint4 o;
    o.x = pack2(a[0] * sc, a[1] * sc);
    o.y = pack2(a[2] * sc, a[3] * sc);
    o.z = pack2(a[4] * sc, a[5] * sc);
    o.w = pack2(a[6] * sc, a[7] * sc);
    *(uint4*)(agg + (size_t)n * 64 + li * 4) = o;
  }
}

// ---------------- MFMA GEMM: out = bf16(relu(A@W + b) [* invsqrt(deg)]) ------
__global__ __launch_bounds__(256)
void k_gemm(const ushort* __restrict__ A, const ushort* __restrict__ Wt,
            const float* __restrict__ bias, const int* __restrict__ deg_scale,
            ushort* __restrict__ out) {
  int wave = threadIdx.x >> 6, lane = threadIdx.x & 63;
  int strip = blockIdx.x * 4 + wave;
  if (strip >= N_NODES / 16) return;  // 6250 strips
  int row0 = strip * 16;
  int lr = lane & 15;
  int lk = lane >> 4;

  bf16x8 bfrag[4][8];
  #pragma unroll
  for (int ks = 0; ks < 4; ++ks)
    #pragma unroll
    for (int c = 0; c < 8; ++c)
      bfrag[ks][c] = *(const bf16x8*)(Wt + (size_t)(c * 16 + lr) * 128 + ks * 32 + lk * 8);

  f32x4 acc[8] = {};
  #pragma unroll
  for (int ks = 0; ks < 4; ++ks) {
    bf16x8 afrag = *(const bf16x8*)(A + (size_t)(row0 + lr) * 128 + ks * 32 + lk * 8);
    #pragma unroll
    for (int c = 0; c < 8; ++c)
      acc[c] = __builtin_amdgcn_mfma_f32_16x16x32_bf16(afrag, bfrag[ks][c], acc[c], 0, 0, 0);
  }

  #pragma unroll
  for (int r = 0; r < 4; ++r) {
    int row = row0 + lk * 4 + r;
    float s = 1.f;
    if (deg_scale) {
      int d = deg_scale[row];
      s = d > 0 ? rsqrtf((float)d) : 0.f;
    }
    #pragma unroll
    for (int c = 0; c < 8; ++c) {
      int col = c * 16 + lr;
      float v = fmaxf(acc[c][r] + bias[col], 0.f) * s;
      out[(size_t)row * 128 + col] = f2bf(v);
    }
  }
}

// ---------------- segmented mean-pool: 64 rows per wave ----------------------
__global__ __launch_bounds__(256)
void k_pool(const uint* __restrict__ h, const int* __restrict__ gid,
            float* __restrict__ pool, float* __restrict__ cnt) {
  int wave = threadIdx.x >> 6, lane = threadIdx.x & 63;
  int start = blockIdx.x * 256 + wave * 64;
  if (start >= N_NODES) return;
  int end = min(start + 64, N_NODES);
  float ax = 0.f, ay = 0.f;
  int g = gid[start];
  int seglen = 0;
  for (int i = start; i < end; ++i) {
    int gi = gid[i];
    if (gi != g) {
      atomicAdd(&pool[g * DIM + 2 * lane], ax);
      atomicAdd(&pool[g * DIM + 2 * lane + 1], ay);
      if (lane == 0) atomicAdd(&cnt[g], (float)seglen);
      ax = ay = 0.f;
      seglen = 0;
      g = gi;
    }
    uint u = h[(size_t)i * 64 + lane];
    ax += unlo(u);
    ay += unhi(u);
    ++seglen;
  }
  atomicAdd(&pool[g * DIM + 2 * lane], ax);
  atomicAdd(&pool[g * DIM + 2 * lane + 1], ay);
  if (lane == 0) atomicAdd(&cnt[g], (float)seglen);
}

// ---------------- classifier -------------------------------------------------
__global__ void k_classifier(const float* __restrict__ pool, const float* __restrict__ cnt,
                             const float* __restrict__ Wc, const float* __restrict__ bc,
                             float* __restrict__ out) {
  int t = threadIdx.x;
  if (t >= NGRAPH * NCLS) return;
  int g = t / NCLS, c = t % NCLS;
  float inv = 1.f / fmaxf(cnt[g], 1.f);
  float s = bc[c];
  for (int k = 0; k < DIM; ++k) s += pool[g * DIM + k] * inv * Wc[k * NCLS + c];
  out[g * NCLS + c] = s;
}

// -----------------------------------------------------------------------------
extern "C" void kernel_launch(void* const* d_in, const int* in_sizes, int n_in,
                              void* d_out, int out_size, void* d_ws, size_t ws_size,
                              hipStream_t stream) {
  const float* h   = (const float*)d_in[0];
  const int* src   = (const int*)d_in[1];
  const int* dst   = (const int*)d_in[2];
  const int* gid   = (const int*)d_in[3];
  const float* W1  = (const float*)d_in[4];
  const float* b1  = (const float*)d_in[5];
  const float* W2  = (const float*)d_in[6];
  const float* b2  = (const float*)d_in[7];
  const float* Wc  = (const float*)d_in[8];
  const float* bc  = (const float*)d_in[9];
  float* out = (float*)d_out;

  size_t off = 0;
  auto alloc = [&](size_t bytes) -> char* {
    char* p = (char*)d_ws + off;
    off += (bytes + 255) & ~(size_t)255;
    return p;
  };
  ushort* aggbuf  = (ushort*)alloc((size_t)N_NODES * DIM * 2);
  ushort* h2buf   = (ushort*)alloc((size_t)N_NODES * DIM * 2);
  int*    csr_src = (int*)alloc((size_t)N_EDGES * 4);
  int*    row_ptr = (int*)alloc((size_t)(N_NODES + 1) * 4);
  int*    bsum    = (int*)alloc(512 * 4);
  ushort* Wt1     = (ushort*)alloc(16384 * 2);
  ushort* Wt2     = (ushort*)alloc(16384 * 2);
  // hbuf has a zeroed pad row (ZROW); pad row adjoins the zeroed region below
  ushort* hbuf    = (ushort*)alloc((size_t)(N_NODES + 1) * DIM * 2);
  char* zero_start = (char*)hbuf + (size_t)N_NODES * DIM * 2;  // pad row start
  int*   deg_out = (int*)alloc((size_t)N_NODES * 4);
  int*   deg_in  = (int*)alloc((size_t)N_NODES * 4);
  int*   fill    = (int*)alloc((size_t)N_NODES * 4);
  float* pool    = (float*)alloc((size_t)NGRAPH * DIM * 4);
  float* cnt     = (float*)alloc((size_t)NGRAPH * 4);
  char* zero_end = (char*)d_ws + off;
  (void)ws_size; (void)in_sizes; (void)n_in; (void)out_size;

  int zero_ints = (int)((zero_end - zero_start) / 4);
  const int NB = (N_NODES + 255) / 256;   // 391
  const int EB4 = (N_EDGES / 4 + 255) / 256;  // 1563

  k_zero<<<512, 256, 0, stream>>>((int*)zero_start, zero_ints);
  k_degrees<<<EB4, 256, 0, stream>>>((const int4*)src, (const int4*)dst, deg_out, deg_in);
  k_blocksum<<<NB, 256, 0, stream>>>(deg_in, bsum);
  k_scan_bsum<<<1, 512, 0, stream>>>(bsum, NB);
  k_rowptr<<<NB, 256, 0, stream>>>(deg_in, bsum, row_ptr);
  k_fill<<<EB4, 256, 0, stream>>>((const int4*)src, (const int4*)dst, row_ptr, fill, csr_src);
  k_convW<<<128, 256, 0, stream>>>(W1, W2, Wt1, Wt2);
  // layer 1
  k_prescale<<<(N_NODES * 16 + 255) / 256, 256, 0, stream>>>((const float4*)h, deg_out,
                                                             (uint4*)hbuf);
  k_gather<<<(N_NODES + 3) / 4, 256, 0, stream>>>((const uint*)hbuf, row_ptr, csr_src,
                                                  (uint*)aggbuf);
  k_gemm<<<(N_NODES / 16 + 3) / 4, 256, 0, stream>>>(aggbuf, Wt1, b1, deg_out, hbuf);
  // layer 2 (hbuf carries next layer's src-side norm from the epilogue)
  k_gather<<<(N_NODES + 3) / 4, 256, 0, stream>>>((const uint*)hbuf, row_ptr, csr_src,
                                                  (uint*)aggbuf);
  k_gemm<<<(N_NODES / 16 + 3) / 4, 256, 0, stream>>>(aggbuf, Wt2, b2, nullptr, h2buf);
  // pool + classify
  k_pool<<<(N_NODES + 255) / 256, 256, 0, stream>>>((const uint*)h2buf, gid, pool, cnt);
  k_classifier<<<1, 640, 0, stream>>>(pool, cnt, Wc, bc, out);
}

// Round 5
// 433.221 us; speedup vs baseline: 2.1171x; 1.3444x over previous
//
#include <hip/hip_runtime.h>

#define N_NODES 100000
#define N_EDGES 1600000
#define DIM     128
#define NGRAPH  64
#define NCLS    10
#define ZROW    N_NODES   // zeroed pad row id in hbuf

#define NBLK    64                  // histogram/fill blocks
#define EPB     (N_EDGES / NBLK)    // 25000 edges per block (exact)
#define RANGE   50000               // node ids per histogram pass (2 passes)

typedef __bf16 bf16x8 __attribute__((ext_vector_type(8)));
typedef float  f32x4  __attribute__((ext_vector_type(4)));

// ---- bf16 pack/unpack helpers (manual RNE) ----------------------------------
__device__ __forceinline__ ushort f2bf(float x) {
  uint b = __float_as_uint(x);
  b += 0x7fffu + ((b >> 16) & 1u);
  return (ushort)(b >> 16);
}
__device__ __forceinline__ uint pack2(float lo, float hi) {
  return (uint)f2bf(lo) | ((uint)f2bf(hi) << 16);
}
__device__ __forceinline__ float unlo(uint u) { return __uint_as_float(u << 16); }
__device__ __forceinline__ float unhi(uint u) { return __uint_as_float(u & 0xffff0000u); }

__device__ __forceinline__ void acc8(float* a, uint4 u) {
  a[0] += unlo(u.x); a[1] += unhi(u.x);
  a[2] += unlo(u.y); a[3] += unhi(u.y);
  a[4] += unlo(u.z); a[5] += unhi(u.z);
  a[6] += unlo(u.w); a[7] += unhi(u.w);
}

// ---------------- init: zero pool, cnt, pad row ------------------------------
__global__ void k_init(float* __restrict__ pool, float* __restrict__ cnt,
                       uint* __restrict__ padrow) {
  int t = threadIdx.x;
  for (int i = t; i < NGRAPH * DIM; i += 256) pool[i] = 0.f;
  if (t < NGRAPH) cnt[t] = 0.f;
  if (t < DIM / 2) padrow[t] = 0u;
}

// ---------------- LDS-privatized degree histograms ---------------------------
// grid (NBLK, 4): pass p: {0,1}=dst range {0,1} (deg_in), {2,3}=src (deg_out).
// LDS: RANGE/2 u32 words, each packing two u16 counters (carry-safe: <=EPB).
__global__ __launch_bounds__(256)
void k_hist(const int* __restrict__ src, const int* __restrict__ dst,
            ushort* __restrict__ part) {
  extern __shared__ uint cnt[];   // RANGE/2 words = 100 KB
  int p = blockIdx.y;
  int b = blockIdx.x;
  const int* ids = (p < 2) ? dst : src;
  int base = (p & 1) * RANGE;
  for (int i = threadIdx.x; i < RANGE / 2; i += 256) cnt[i] = 0;
  __syncthreads();
  int cb = b * EPB;
  for (int j = threadIdx.x; j < EPB; j += 256) {
    int v = ids[cb + j] - base;
    if ((unsigned)v < RANGE) atomicAdd(&cnt[v >> 1], 1u << ((v & 1) * 16));
  }
  __syncthreads();
  uint* out = (uint*)(part + ((size_t)p * NBLK + b) * RANGE);
  for (int i = threadIdx.x; i < RANGE / 2; i += 256) out[i] = cnt[i];
}

// ---------------- sum partials -> degrees + per-block exclusive prefix -------
__global__ void k_degsum(const ushort* __restrict__ part, int* __restrict__ deg_in,
                         int* __restrict__ deg_out, ushort* __restrict__ pre) {
  int n = blockIdx.x * 256 + threadIdx.x;
  if (n >= N_NODES) return;
  int r = n / RANGE, i = n % RANGE;
  const ushort* pin  = part + ((size_t)r * NBLK) * RANGE + i;        // dst pass
  const ushort* pout = part + ((size_t)(2 + r) * NBLK) * RANGE + i;  // src pass
  int sin = 0, sout = 0;
  for (int b = 0; b < NBLK; ++b) {
    pre[(size_t)b * N_NODES + n] = (ushort)sin;
    sin  += pin[(size_t)b * RANGE];
    sout += pout[(size_t)b * RANGE];
  }
  deg_in[n] = sin;
  deg_out[n] = sout;
}

// ---------------- prefix scan of deg_in -> row_ptr ---------------------------
__global__ void k_blocksum(const int* __restrict__ deg_in, int* __restrict__ bsum) {
  __shared__ int s[256];
  int i = blockIdx.x * 256 + threadIdx.x;
  s[threadIdx.x] = (i < N_NODES) ? deg_in[i] : 0;
  __syncthreads();
  for (int off = 128; off > 0; off >>= 1) {
    if (threadIdx.x < off) s[threadIdx.x] += s[threadIdx.x + off];
    __syncthreads();
  }
  if (threadIdx.x == 0) bsum[blockIdx.x] = s[0];
}

__global__ void k_scan_bsum(int* __restrict__ bsum, int nb) {
  __shared__ int s[512];
  int t = threadIdx.x;
  int v = (t < nb) ? bsum[t] : 0;
  s[t] = v;
  __syncthreads();
  for (int off = 1; off < 512; off <<= 1) {
    int x = (t >= off) ? s[t - off] : 0;
    __syncthreads();
    s[t] += x;
    __syncthreads();
  }
  if (t < nb) bsum[t] = s[t] - v;  // exclusive
}

__global__ void k_rowptr(const int* __restrict__ deg_in, const int* __restrict__ bsum,
                         int* __restrict__ row_ptr) {
  __shared__ int s[256];
  int t = threadIdx.x;
  int i = blockIdx.x * 256 + t;
  int v = (i < N_NODES) ? deg_in[i] : 0;
  s[t] = v;
  __syncthreads();
  for (int off = 1; off < 256; off <<= 1) {
    int x = (t >= off) ? s[t - off] : 0;
    __syncthreads();
    s[t] += x;
    __syncthreads();
  }
  if (i < N_NODES) row_ptr[i] = bsum[blockIdx.x] + s[t] - v;
  if (i == N_NODES - 1) row_ptr[N_NODES] = bsum[blockIdx.x] + s[t];
}

// ---------------- ranked CSR fill (no global atomics) ------------------------
// grid (NBLK, 2): pos = row_ptr[d] + pre[b][d] + local_rank (LDS-ranked).
__global__ __launch_bounds__(256)
void k_fillrank(const int* __restrict__ src, const int* __restrict__ dst,
                const int* __restrict__ row_ptr, const ushort* __restrict__ pre,
                int* __restrict__ csr_src) {
  extern __shared__ uint rk[];    // RANGE/2 words
  int b = blockIdx.x;
  int base = blockIdx.y * RANGE;
  for (int i = threadIdx.x; i < RANGE / 2; i += 256) rk[i] = 0;
  __syncthreads();
  int cb = b * EPB;
  for (int j = threadIdx.x; j < EPB; j += 256) {
    int d = dst[cb + j];
    int s = src[cb + j];
    int v = d - base;
    if ((unsigned)v < RANGE) {
      uint old = atomicAdd(&rk[v >> 1], 1u << ((v & 1) * 16));
      int rank = (old >> ((v & 1) * 16)) & 0xffff;
      int pos = row_ptr[d] + pre[(size_t)b * N_NODES + d] + rank;
      csr_src[pos] = s;
    }
  }
}

// ---------------- W -> bf16 transposed (B^T layout: Wt[c][k]) ----------------
__global__ void k_convW(const float* __restrict__ W1, const float* __restrict__ W2,
                        ushort* __restrict__ Wt1, ushort* __restrict__ Wt2) {
  int idx = blockIdx.x * 256 + threadIdx.x;
  const float* W = (idx < 16384) ? W1 : W2;
  ushort* Wt = (idx < 16384) ? Wt1 : Wt2;
  int t = idx & 16383;
  int c = t >> 7, k = t & 127;
  Wt[c * 128 + k] = f2bf(W[k * 128 + c]);
}

// ---------------- prescale: hs = bf16(h * rsqrt(deg_out[row])) ---------------
__global__ void k_prescale(const float4* __restrict__ h4, const int* __restrict__ deg_out,
                           uint4* __restrict__ out4) {
  int idx = blockIdx.x * blockDim.x + threadIdx.x;
  if (idx < N_NODES * 16) {
    int row = idx >> 4;
    int d = deg_out[row];
    float s = d > 0 ? rsqrtf((float)d) : 0.f;
    float4 v0 = h4[idx * 2];
    float4 v1 = h4[idx * 2 + 1];
    uint4 o;
    o.x = pack2(v0.x * s, v0.y * s);
    o.y = pack2(v0.z * s, v0.w * s);
    o.z = pack2(v1.x * s, v1.y * s);
    o.w = pack2(v1.z * s, v1.w * s);
    out4[idx] = o;
  }
}

// ---------------- fused gather + MFMA GEMM -----------------------------------
// Block = 4 waves = one 16-row strip. Each wave gathers 4 nodes (4-edge-slot
// MLP, 16 indep 16B loads in flight), stages bf16 rows in LDS, then MFMA
// (each wave computes 32 output cols). Epilogue: bias+relu[+src-norm], bf16.
__global__ __launch_bounds__(256)
void k_gg(const uint* __restrict__ hs, const int* __restrict__ row_ptr,
          const int* __restrict__ csr_src, const ushort* __restrict__ Wt,
          const float* __restrict__ bias, const int* __restrict__ deg_scale,
          ushort* __restrict__ out) {
  __shared__ ushort As[16][136];   // +16B row pad: <=2-way LDS bank alias
  int wv = threadIdx.x >> 6, lane = threadIdx.x & 63;
  int strip = blockIdx.x;
  int sub = lane >> 4, li = lane & 15;

  // B fragments (wave's 2 col-tiles), loaded while gather is in flight
  int lr = lane & 15, lk = lane >> 4;
  bf16x8 bfrag[4][2];
  #pragma unroll
  for (int ks = 0; ks < 4; ++ks)
    #pragma unroll
    for (int c2 = 0; c2 < 2; ++c2)
      bfrag[ks][c2] = *(const bf16x8*)(Wt + (size_t)((wv * 2 + c2) * 16 + lr) * 128 +
                                       ks * 32 + lk * 8);

  #pragma unroll
  for (int it = 0; it < 4; ++it) {
    int n = strip * 16 + wv * 4 + it;
    int beg = row_ptr[n], end = row_ptr[n + 1], deg = end - beg;
    float a[8] = {};
    for (int cb2 = 0; cb2 < deg; cb2 += 64) {
      int cdeg = min(64, deg - cb2);
      int myidx = (lane < cdeg) ? csr_src[beg + cb2 + lane] : ZROW;
      for (int e = 0; e < cdeg; e += 16) {
        int s0 = __shfl(myidx, e + sub);
        int s1 = __shfl(myidx, e + 4 + sub);
        int s2 = __shfl(myidx, e + 8 + sub);
        int s3 = __shfl(myidx, e + 12 + sub);
        uint4 u0 = *(const uint4*)(hs + (size_t)s0 * 64 + li * 4);
        uint4 u1 = *(const uint4*)(hs + (size_t)s1 * 64 + li * 4);
        uint4 u2 = *(const uint4*)(hs + (size_t)s2 * 64 + li * 4);
        uint4 u3 = *(const uint4*)(hs + (size_t)s3 * 64 + li * 4);
        acc8(a, u0); acc8(a, u1); acc8(a, u2); acc8(a, u3);
      }
    }
    #pragma unroll
    for (int k = 0; k < 8; ++k) {
      a[k] += __shfl_xor(a[k], 16);
      a[k] += __shfl_xor(a[k], 32);
    }
    if (sub == 0) {
      float sc = deg > 0 ? rsqrtf((float)deg) : 0.f;
      uint4 o;
      o.x = pack2(a[0] * sc, a[1] * sc);
      o.y = pack2(a[2] * sc, a[3] * sc);
      o.z = pack2(a[4] * sc, a[5] * sc);
      o.w = pack2(a[6] * sc, a[7] * sc);
      *(uint4*)&As[wv * 4 + it][li * 8] = o;
    }
  }
  __syncthreads();

  f32x4 acc[2] = {};
  #pragma unroll
  for (int ks = 0; ks < 4; ++ks) {
    bf16x8 af = *(const bf16x8*)&As[lr][ks * 32 + lk * 8];
    acc[0] = __builtin_amdgcn_mfma_f32_16x16x32_bf16(af, bfrag[ks][0], acc[0], 0, 0, 0);
    acc[1] = __builtin_amdgcn_mfma_f32_16x16x32_bf16(af, bfrag[ks][1], acc[1], 0, 0, 0);
  }

  #pragma unroll
  for (int rr = 0; rr < 4; ++rr) {
    int row = strip * 16 + lk * 4 + rr;
    float s = 1.f;
    if (deg_scale) {
      int d = deg_scale[row];
      s = d > 0 ? rsqrtf((float)d) : 0.f;
    }
    #pragma unroll
    for (int c2 = 0; c2 < 2; ++c2) {
      int col = (wv * 2 + c2) * 16 + lr;
      float v = fmaxf(acc[c2][rr] + bias[col], 0.f) * s;
      out[(size_t)row * 128 + col] = f2bf(v);
    }
  }
}

// ---------------- segmented mean-pool: 64 rows per wave ----------------------
__global__ __launch_bounds__(256)
void k_pool(const uint* __restrict__ h, const int* __restrict__ gid,
            float* __restrict__ pool, float* __restrict__ cnt) {
  int wave = threadIdx.x >> 6, lane = threadIdx.x & 63;
  int start = blockIdx.x * 256 + wave * 64;
  if (start >= N_NODES) return;
  int end = min(start + 64, N_NODES);
  float ax = 0.f, ay = 0.f;
  int g = gid[start];
  int seglen = 0;
  for (int i = start; i < end; ++i) {
    int gi = gid[i];
    if (gi != g) {
      atomicAdd(&pool[g * DIM + 2 * lane], ax);
      atomicAdd(&pool[g * DIM + 2 * lane + 1], ay);
      if (lane == 0) atomicAdd(&cnt[g], (float)seglen);
      ax = ay = 0.f;
      seglen = 0;
      g = gi;
    }
    uint u = h[(size_t)i * 64 + lane];
    ax += unlo(u);
    ay += unhi(u);
    ++seglen;
  }
  atomicAdd(&pool[g * DIM + 2 * lane], ax);
  atomicAdd(&pool[g * DIM + 2 * lane + 1], ay);
  if (lane == 0) atomicAdd(&cnt[g], (float)seglen);
}

// ---------------- classifier -------------------------------------------------
__global__ void k_classifier(const float* __restrict__ pool, const float* __restrict__ cnt,
                             const float* __restrict__ Wc, const float* __restrict__ bc,
                             float* __restrict__ out) {
  int t = threadIdx.x;
  if (t >= NGRAPH * NCLS) return;
  int g = t / NCLS, c = t % NCLS;
  float inv = 1.f / fmaxf(cnt[g], 1.f);
  float s = bc[c];
  for (int k = 0; k < DIM; ++k) s += pool[g * DIM + k] * inv * Wc[k * NCLS + c];
  out[g * NCLS + c] = s;
}

// -----------------------------------------------------------------------------
extern "C" void kernel_launch(void* const* d_in, const int* in_sizes, int n_in,
                              void* d_out, int out_size, void* d_ws, size_t ws_size,
                              hipStream_t stream) {
  const float* h   = (const float*)d_in[0];
  const int* src   = (const int*)d_in[1];
  const int* dst   = (const int*)d_in[2];
  const int* gid   = (const int*)d_in[3];
  const float* W1  = (const float*)d_in[4];
  const float* b1  = (const float*)d_in[5];
  const float* W2  = (const float*)d_in[6];
  const float* b2  = (const float*)d_in[7];
  const float* Wc  = (const float*)d_in[8];
  const float* bc  = (const float*)d_in[9];
  float* out = (float*)d_out;

  size_t off = 0;
  auto alloc = [&](size_t bytes) -> char* {
    char* p = (char*)d_ws + off;
    off += (bytes + 255) & ~(size_t)255;
    return p;
  };
  ushort* h2buf   = (ushort*)alloc((size_t)N_NODES * DIM * 2);        // 25.6 MB
  int*    csr_src = (int*)alloc((size_t)N_EDGES * 4);                 //  6.4 MB
  int*    row_ptr = (int*)alloc((size_t)(N_NODES + 1) * 4);
  int*    bsum    = (int*)alloc(512 * 4);
  ushort* Wt1     = (ushort*)alloc(16384 * 2);
  ushort* Wt2     = (ushort*)alloc(16384 * 2);
  ushort* hbuf    = (ushort*)alloc((size_t)(N_NODES + 1) * DIM * 2);  // 25.6 MB (+pad row)
  uint*   padrow  = (uint*)(hbuf + (size_t)N_NODES * DIM);
  // partials region; dead after k_degsum -> reused as layer-1 output (h1buf)
  ushort* part    = (ushort*)alloc((size_t)4 * NBLK * RANGE * 2);     // 25.6 MB
  ushort* h1buf   = part;                                             // alias (same size)
  ushort* pre     = (ushort*)alloc((size_t)NBLK * N_NODES * 2);       // 12.8 MB
  int*    deg_out = (int*)alloc((size_t)N_NODES * 4);
  int*    deg_in  = (int*)alloc((size_t)N_NODES * 4);
  float*  pool    = (float*)alloc((size_t)NGRAPH * DIM * 4);
  float*  cnt     = (float*)alloc((size_t)NGRAPH * 4);
  (void)ws_size; (void)in_sizes; (void)n_in; (void)out_size;

  const int NB = (N_NODES + 255) / 256;   // 391
  const size_t HIST_LDS = (RANGE / 2) * sizeof(uint);  // 100 KB dynamic LDS

  // init small accumulators + pad row
  k_init<<<1, 256, 0, stream>>>(pool, cnt, padrow);
  // degree histograms: 4 passes x 64 blocks, LDS-privatized (no global atomics)
  k_hist<<<dim3(NBLK, 4), 256, HIST_LDS, stream>>>(src, dst, part);
  // reduce partials -> deg_in / deg_out + per-block exclusive prefix
  k_degsum<<<NB, 256, 0, stream>>>(part, deg_in, deg_out, pre);
  // exclusive scan of deg_in -> row_ptr
  k_blocksum<<<NB, 256, 0, stream>>>(deg_in, bsum);
  k_scan_bsum<<<1, 512, 0, stream>>>(bsum, NB);
  k_rowptr<<<NB, 256, 0, stream>>>(deg_in, bsum, row_ptr);
  // ranked CSR fill (no global atomics)
  k_fillrank<<<dim3(NBLK, 2), 256, HIST_LDS, stream>>>(src, dst, row_ptr, pre, csr_src);
  // weights -> bf16 B^T
  k_convW<<<128, 256, 0, stream>>>(W1, W2, Wt1, Wt2);
  // layer-1 input prescale (src-side norm), fp32 -> bf16
  k_prescale<<<(N_NODES * 16 + 255) / 256, 256, 0, stream>>>((const float4*)h, deg_out,
                                                             (uint4*)hbuf);
  // layer 1: fused gather + GEMM (+bias+relu+next-layer src norm)
  k_gg<<<N_NODES / 16, 256, 0, stream>>>((const uint*)hbuf, row_ptr, csr_src,
                                         Wt1, b1, deg_out, h1buf);
  // layer 2: fused gather + GEMM (+bias+relu)
  k_gg<<<N_NODES / 16, 256, 0, stream>>>((const uint*)h1buf, row_ptr, csr_src,
                                         Wt2, b2, nullptr, h2buf);
  // pool + classify
  k_pool<<<(N_NODES + 255) / 256, 256, 0, stream>>>((const uint*)h2buf, gid, pool, cnt);
  k_classifier<<<1, 640, 0, stream>>>(pool, cnt, Wc, bc, out);
}